// Round 13
// baseline (28.736 us; speedup 1.0000x reference)
//
#include <hip/hip_runtime.h>

// Cost volume loss: pred/target (8,3,512,512) f32.
// Per pixel: min over 5x5 offsets (zero-padded target) of mean_C |pred - patch|,
// then global mean. Output: single f32 scalar.
//
// r13: LDS-staged, counted-vmcnt pipelined (fixes r4's full-drain mistake).
// Block = 256 thr = 512 cols x 8 rows (2 row-groups of 4). Grid = 512 blocks.
// Target tile = 12 rows x 3ch x 512 f32 = 72KB LDS, staged in 3 chunks of
// 4 rows via global_load_lds. Schedule: pred+c0+c1 -> vmcnt(6) -> barrier ->
// issue c2 -> compute A(rows0-3) -> vmcnt(6) -> barrier -> compute B(4-7) ->
// vmcnt(0) -> barrier -> compute C(8-11). Raw s_barrier keeps prefetch alive.
// Global VMEM/thread: 30 (was 60 in r11). Windows read from LDS as b64 pairs.

#define H_DIM 512
#define W_DIM 512
#define N_DIM 8
#define C_DIM 3
#define HW (H_DIM * W_DIM)
#define CHW (C_DIM * HW)
#define NPIX (N_DIM * HW)
#define NBLOCKS 512
#define BIGF 3.0e38f
#define TROWS 12
#define LDS_FLOATS (C_DIM * TROWS * W_DIM)   // 18432
#define LDS_BYTES ((LDS_FLOATS + 4) * 4)     // + 16B for the reduce scratch

typedef float f4 __attribute__((ext_vector_type(4)));
typedef float f2 __attribute__((ext_vector_type(2)));
typedef const float __attribute__((address_space(1)))* gas;
typedef float __attribute__((address_space(3)))* las;

// Compute thread tile-rows m = M0..M0+3 (LDS row = rgbase + m).
template <int M0>
__device__ __forceinline__ void compute4(const float* lds_, int rgbase, int h0t,
                                         int w0, bool wlo, bool whi, int la, int rb,
                                         const f4 (&pv)[4][3], float (&best)[4][4]) {
#pragma unroll
    for (int m = M0; m < M0 + 4; ++m) {
        const int hh = h0t - 2 + m;                     // wave-uniform
        const bool rowok = (hh >= 0) && (hh < H_DIM);   // wave-uniform
        // window: logical cols [w0-2, w0+6), from LDS (8B-aligned b64 reads)
        float w[3][8];
#pragma unroll
        for (int c = 0; c < 3; ++c) {
            const float* rowp = lds_ + ((size_t)c * TROWS + rgbase + m) * W_DIM;
            const f2 a0 = *(const f2*)(rowp + la);
            const f2 a1 = *(const f2*)(rowp + la + 2);
            const f2 b0 = *(const f2*)(rowp + rb);
            const f2 b1 = *(const f2*)(rowp + rb + 2);
            w[c][0] = a0[0];  w[c][1] = a0[1];
            w[c][2] = wlo ? a0[0] : a1[0];   // col 0 at left image edge
            w[c][3] = wlo ? a0[1] : a1[1];   // col 1 at left image edge
            w[c][4] = whi ? b1[0] : b0[0];   // col 510 at right image edge
            w[c][5] = whi ? b1[1] : b0[1];   // col 511 at right image edge
            w[c][6] = b1[0];  w[c][7] = b1[1];
        }
#pragma unroll
        for (int k = 0; k < 4; ++k) {
            const int di = m - 2 - k;            // compile-time after unroll
            if (di >= -2 && di <= 2) {
#pragma unroll
                for (int px = 0; px < 4; ++px) {
                    float rm = BIGF;
#pragma unroll
                    for (int dj = -2; dj <= 2; ++dj) {
                        const int ix = px + dj + 2;  // 0..7
                        float s = fabsf(pv[k][0][px] - w[0][ix])
                                + fabsf(pv[k][1][px] - w[1][ix])
                                + fabsf(pv[k][2][px] - w[2][ix]);
                        if (px + dj < 0)      s = wlo ? BIGF : s;
                        else if (px + dj > 3) s = whi ? BIGF : s;
                        rm = fminf(rm, s);
                    }
                    best[k][px] = fminf(best[k][px], rowok ? rm : BIGF);
                }
            }
        }
    }
}

__global__ __launch_bounds__(256, 2) void cvl_main(const float* __restrict__ pred,
                                                   const float* __restrict__ targ,
                                                   float* __restrict__ partial) {
    extern __shared__ float lds[];
    const int tid  = threadIdx.x;
    const int lane = tid & 63;
    const int wv   = tid >> 6;        // 0..3
    const int col  = tid & 127;       // 0..127
    const int rg   = tid >> 7;        // 0..1 (wave-uniform)
    const int bid  = blockIdx.x;      // 0..511
    const int n    = bid >> 6;
    const int hg   = bid & 63;
    const int hbase = hg * 8;
    const int h0t   = hbase + rg * 4; // first of this thread's 4 rows
    const int w0    = col * 4;
    const size_t nbase = (size_t)n * CHW;

    // ---- pred: 12 f4 loads, issued first (fly under the staging) ----
    f4 pv[4][3];
#pragma unroll
    for (int r = 0; r < 4; ++r)
#pragma unroll
        for (int c = 0; c < 3; ++c)
            pv[r][c] = __builtin_nontemporal_load(
                (const f4*)(pred + nbase + (size_t)c * HW +
                            (size_t)(h0t + r) * W_DIM + w0));

    // ---- stage a 4-row x 3ch chunk (24 x 1KB units; unit = it*4 + wave) ----
    auto stage_chunk = [&](int ck) {
#pragma unroll
        for (int it = 0; it < 6; ++it) {
            const int u    = it * 4 + wv;     // 0..23, wave-uniform
            const int c    = u >> 3;          // channel
            const int rr   = (u & 7) >> 1;    // row in chunk
            const int hf   = u & 1;           // half-row
            const int trow = ck * 4 + rr;     // tile row 0..11
            int hh = hbase - 2 + trow;        // clamp; invalid rows masked later
            hh = hh < 0 ? 0 : (hh > H_DIM - 1 ? H_DIM - 1 : hh);
            const float* g = targ + nbase + (size_t)c * HW + (size_t)hh * W_DIM +
                             hf * 256 + lane * 4;
            float* l = lds + ((size_t)c * TROWS + trow) * W_DIM + hf * 256;
            __builtin_amdgcn_global_load_lds((gas)g, (las)l, 16, 0, 0);
        }
    };
    stage_chunk(0);   // outstanding: pred 12 + 6
    stage_chunk(1);   // + 6 -> 24

    const bool wlo = (col == 0);
    const bool whi = (col == 127);
    const int la = wlo ? 0 : (w0 - 2);
    const int rb = whi ? (W_DIM - 4) : (w0 + 2);

    // ---- seed best with zero-pad candidate on border pixels (overlaps DMA) ----
    float best[4][4];
#pragma unroll
    for (int k = 0; k < 4; ++k) {
        const int hp = h0t + k;
        const bool hcand = (hp < 2) || (hp >= H_DIM - 2);
#pragma unroll
        for (int px = 0; px < 4; ++px) {
            const bool wcand = (px < 2) ? wlo : whi;
            const float soob =
                fabsf(pv[k][0][px]) + fabsf(pv[k][1][px]) + fabsf(pv[k][2][px]);
            best[k][px] = (hcand || wcand) ? soob : BIGF;
        }
    }

    // ---- pipeline: wait c0 (oldest 18 of 24 = pred + c0) ----
    asm volatile("s_waitcnt vmcnt(6)" ::: "memory");
    __builtin_amdgcn_s_barrier();
    stage_chunk(2);                    // rows 8-11 fly under phase A

    // phase A: tile rows 0-3 (chunk 0) — rg0 only
    if (rg == 0) compute4<0>(lds, 0, h0t, w0, wlo, whi, la, rb, pv, best);

    asm volatile("s_waitcnt vmcnt(6)" ::: "memory");   // c1 done (c2 may fly)
    __builtin_amdgcn_s_barrier();

    // phase B: tile rows 4-7 (chunk 1) — rg0 rows 4-7, rg1 rows 0-3
    if (rg == 0) compute4<4>(lds, 0, h0t, w0, wlo, whi, la, rb, pv, best);
    else         compute4<0>(lds, 4, h0t, w0, wlo, whi, la, rb, pv, best);

    asm volatile("s_waitcnt vmcnt(0)" ::: "memory");   // c2 done
    __builtin_amdgcn_s_barrier();

    // phase C: tile rows 8-11 (chunk 2) — rg1 only
    if (rg == 1) compute4<4>(lds, 4, h0t, w0, wlo, whi, la, rb, pv, best);

    // ---- block reduce: 16 px -> thread, wave shuffle, LDS, one store ----
    float v = 0.0f;
#pragma unroll
    for (int k = 0; k < 4; ++k)
#pragma unroll
        for (int px = 0; px < 4; ++px)
            v += best[k][px];

#pragma unroll
    for (int o = 32; o > 0; o >>= 1) v += __shfl_down(v, o, 64);

    float* ws = lds + LDS_FLOATS;     // 16B reduce scratch past the tile
    if (lane == 0) ws[wv] = v;
    __syncthreads();
    if (tid == 0) partial[bid] = ws[0] + ws[1] + ws[2] + ws[3];
}

__global__ __launch_bounds__(256) void cvl_final(const float* __restrict__ partial,
                                                 float* __restrict__ out) {
    const int tid = threadIdx.x;
    double v = (double)partial[tid] + (double)partial[tid + 256];
#pragma unroll
    for (int o = 32; o > 0; o >>= 1) v += __shfl_down(v, o, 64);

    __shared__ double ws[4];
    const int lane = tid & 63;
    const int wid  = tid >> 6;
    if (lane == 0) ws[wid] = v;
    __syncthreads();
    if (tid == 0) {
        const double s = ws[0] + ws[1] + ws[2] + ws[3];
        out[0] = (float)(s / (3.0 * (double)NPIX));
    }
}

extern "C" void kernel_launch(void* const* d_in, const int* in_sizes, int n_in,
                              void* d_out, int out_size, void* d_ws, size_t ws_size,
                              hipStream_t stream) {
    const float* pred = (const float*)d_in[0];
    const float* targ = (const float*)d_in[1];
    float* out = (float*)d_out;
    float* partial = (float*)d_ws;

    hipFuncSetAttribute((const void*)cvl_main,
                        hipFuncAttributeMaxDynamicSharedMemorySize, LDS_BYTES);

    cvl_main<<<NBLOCKS, 256, LDS_BYTES, stream>>>(pred, targ, partial);
    cvl_final<<<1, 256, 0, stream>>>(partial, out);
}

// Round 14
// 27.792 us; speedup vs baseline: 1.0340x; 1.0340x over previous
//
#include <hip/hip_runtime.h>

// Cost volume loss: pred/target (8,3,512,512) f32.
// Per pixel: min over 5x5 offsets (zero-padded target) of mean_C |pred - patch|,
// then global mean. Output: single f32 scalar.
//
// r14: shuffle-halo. Wave = 64 lanes x 8 cols = full 512-col row span, so
// lane-neighbors are col-neighbors and wave edges are image W-edges (no
// cross-wave halo). Thread = 8 cols x 2 rows (16 px): window [w0-2,w0+10) =
// own 2xf4 + 2 floats via shfl_up + 2 via shfl_down. Loads/thread = 12 pred +
// 36 target = 48 (3.0/px) at 8 waves/CU (512 blocks x 4 waves).
// Epilogue: 4B memset + per-block scaled atomicAdd into d_out (no final kernel).

#define H_DIM 512
#define W_DIM 512
#define N_DIM 8
#define C_DIM 3
#define HW (H_DIM * W_DIM)
#define CHW (C_DIM * HW)
#define NPIX (N_DIM * HW)
#define NBLOCKS 512
#define BIGF 3.0e38f

typedef float f4 __attribute__((ext_vector_type(4)));

__global__ __launch_bounds__(256, 2) void cvl_main(const float* __restrict__ pred,
                                                   const float* __restrict__ targ,
                                                   float* __restrict__ out) {
    const int tid   = threadIdx.x;
    const int lane  = tid & 63;       // col-thread: w0 = lane*8
    const int wv    = tid >> 6;       // 0..3, wave owns rows h0..h0+1
    const int bid   = blockIdx.x;     // 0..511
    const int n     = bid >> 6;       // 0..7
    const int hg    = bid & 63;       // 0..63
    const int hbase = hg * 8;
    const int h0    = hbase + wv * 2; // this thread's 2 rows (wave-uniform)
    const int w0    = lane * 8;       // this thread's 8 cols

    const size_t nbase = (size_t)n * CHW;

    // ---- pred: 2 rows x 3 ch x 8 px (2 f4), nontemporal (streamed once) ----
    float pf[2][3][8];
#pragma unroll
    for (int r = 0; r < 2; ++r)
#pragma unroll
        for (int c = 0; c < 3; ++c) {
            const float* pp = pred + nbase + (size_t)c * HW +
                              (size_t)(h0 + r) * W_DIM + w0;
            const f4 a = __builtin_nontemporal_load((const f4*)pp);
            const f4 b = __builtin_nontemporal_load((const f4*)(pp + 4));
            pf[r][c][0] = a[0]; pf[r][c][1] = a[1]; pf[r][c][2] = a[2]; pf[r][c][3] = a[3];
            pf[r][c][4] = b[0]; pf[r][c][5] = b[1]; pf[r][c][6] = b[2]; pf[r][c][7] = b[3];
        }

    const bool wlo = (lane == 0);     // image left edge
    const bool whi = (lane == 63);    // image right edge

    // ---- seed best: border pixels get the zero-pad candidate sum|pred| ----
    float best[2][8];
#pragma unroll
    for (int r = 0; r < 2; ++r) {
        const int hp = h0 + r;
        const bool hcand = (hp < 2) || (hp >= H_DIM - 2);
#pragma unroll
        for (int px = 0; px < 8; ++px) {
            const bool wcand = (px < 2) ? wlo : ((px > 5) ? whi : false);
            const float soob =
                fabsf(pf[r][0][px]) + fabsf(pf[r][1][px]) + fabsf(pf[r][2][px]);
            best[r][px] = (hcand || wcand) ? soob : BIGF;
        }
    }

    const float* trow = targ + nbase;

    // ---- 6 target rows: own 2xf4 loads + 4 shuffles per (row,ch) ----
#pragma unroll
    for (int j = 0; j < 6; ++j) {
        const int hh = h0 - 2 + j;                       // wave-uniform
        const bool rowok = (hh >= 0) && (hh < H_DIM);    // wave-uniform
        const int hc = (hh < 0) ? 0 : ((hh >= H_DIM) ? (H_DIM - 1) : hh);

        float w[3][12];   // logical cols [w0-2, w0+10)
#pragma unroll
        for (int c = 0; c < 3; ++c) {
            const float* rowp = trow + (size_t)c * HW + (size_t)hc * W_DIM + w0;
            const f4 b0 = *(const f4*)rowp;
            const f4 b1 = *(const f4*)(rowp + 4);
            // halo via cross-lane shuffle (lane0/63 garbage is masked by BIGF below)
            w[c][0]  = __shfl_up(b1[2], 1, 64);   // lane-1 cols w0-2
            w[c][1]  = __shfl_up(b1[3], 1, 64);   // lane-1 col  w0-1
            w[c][10] = __shfl_down(b0[0], 1, 64); // lane+1 col  w0+8
            w[c][11] = __shfl_down(b0[1], 1, 64); // lane+1 col  w0+9
            w[c][2] = b0[0]; w[c][3] = b0[1]; w[c][4] = b0[2]; w[c][5] = b0[3];
            w[c][6] = b1[0]; w[c][7] = b1[1]; w[c][8] = b1[2]; w[c][9] = b1[3];
        }

#pragma unroll
        for (int r = 0; r < 2; ++r) {
            const int di = j - 2 - r;            // compile-time after unroll
            if (di >= -2 && di <= 2) {
#pragma unroll
                for (int px = 0; px < 8; ++px) {
                    float rm = BIGF;
#pragma unroll
                    for (int dj = -2; dj <= 2; ++dj) {
                        const int ix = px + dj + 2;  // 0..11
                        float s = fabsf(pf[r][0][px] - w[0][ix])
                                + fabsf(pf[r][1][px] - w[1][ix])
                                + fabsf(pf[r][2][px] - w[2][ix]);
                        // out-of-image candidates invalid at W edges:
                        if (px + dj < 0)      s = wlo ? BIGF : s;
                        else if (px + dj > 7) s = whi ? BIGF : s;
                        rm = fminf(rm, s);
                    }
                    best[r][px] = fminf(best[r][px], rowok ? rm : BIGF);
                }
            }
        }
    }

    // ---- block reduce: 16 px -> thread, wave shuffle, LDS, one atomic ----
    float v = 0.0f;
#pragma unroll
    for (int r = 0; r < 2; ++r)
#pragma unroll
        for (int px = 0; px < 8; ++px)
            v += best[r][px];

#pragma unroll
    for (int o = 32; o > 0; o >>= 1) v += __shfl_down(v, o, 64);

    __shared__ float ws[4];
    if (lane == 0) ws[wv] = v;
    __syncthreads();
    if (tid == 0) {
        const float bs = ws[0] + ws[1] + ws[2] + ws[3];
        atomicAdd(out, bs * (1.0f / (3.0f * (float)NPIX)));
    }
}

extern "C" void kernel_launch(void* const* d_in, const int* in_sizes, int n_in,
                              void* d_out, int out_size, void* d_ws, size_t ws_size,
                              hipStream_t stream) {
    const float* pred = (const float*)d_in[0];
    const float* targ = (const float*)d_in[1];
    float* out = (float*)d_out;

    hipMemsetAsync(out, 0, sizeof(float), stream);
    cvl_main<<<NBLOCKS, 256, 0, stream>>>(pred, targ, out);
}

// Round 15
// 27.433 us; speedup vs baseline: 1.0475x; 1.0131x over previous
//
#include <hip/hip_runtime.h>

// Cost volume loss: pred/target (8,3,512,512) f32.
// Per pixel: min over 5x5 offsets (zero-padded target) of mean_C |pred - patch|,
// then global mean. Output: single f32 scalar.
//
// r15 = r11's proven main (4 cols x 4 rows/thread, 3.75 loads/px, 8 waves/CU,
// branch-free clamped-row loop) + cheap epilogue: 4B fill of d_out + one scaled
// atomicAdd per block (replaces the 1-block cvl_final dispatch + its gap).
// Ledger: loads/px drives runtime (r1 78/px=112us, r3 5.25=22, r11 3.75=19);
// all attempts below 3.75 (r12 tall-tile, r13 LDS, r14 shuffle) regressed.

#define H_DIM 512
#define W_DIM 512
#define N_DIM 8
#define C_DIM 3
#define HW (H_DIM * W_DIM)
#define CHW (C_DIM * HW)
#define NPIX (N_DIM * HW)
#define NBLOCKS 512
#define BIGF 3.0e38f

typedef float f4 __attribute__((ext_vector_type(4)));

__global__ __launch_bounds__(256, 2) void cvl_main(const float* __restrict__ pred,
                                                   const float* __restrict__ targ,
                                                   float* __restrict__ out) {
    const int tid = threadIdx.x;
    const int col = tid & 127;        // 0..127
    const int rg  = tid >> 7;         // 0..1 (wave-uniform)
    const int bid = blockIdx.x;       // 0..511
    const int n   = bid >> 6;         // 0..7
    const int hg  = bid & 63;         // 0..63
    const int h0  = hg * 8 + rg * 4;  // first of this thread's 4 rows (wave-uniform)
    const int w0  = col * 4;          // first of this thread's 4 cols

    const size_t nbase = (size_t)n * CHW;

    // ---- pred: 4 rows x 3 channels x 4 px, nontemporal (streamed once) ----
    f4 pv[4][3];
#pragma unroll
    for (int r = 0; r < 4; ++r)
#pragma unroll
        for (int c = 0; c < 3; ++c)
            pv[r][c] = __builtin_nontemporal_load(
                (const f4*)(pred + nbase + (size_t)c * HW +
                            (size_t)(h0 + r) * W_DIM + w0));

    const bool wlo = (col == 0);          // w0 == 0
    const bool whi = (col == 127);        // w0 == 508
    const int am = wlo ? 0 : (w0 - 2);            // left window load col
    const int bp = whi ? (W_DIM - 4) : (w0 + 2);  // right window load col
    const float* trow = targ + nbase;

    // ---- seed best: border pixels get the zero-pad candidate sum|pred| ----
    float best[4][4];
#pragma unroll
    for (int r = 0; r < 4; ++r) {
        const int hp = h0 + r;
        const bool hcand = (hp < 2) || (hp >= H_DIM - 2);
#pragma unroll
        for (int px = 0; px < 4; ++px) {
            const bool wcand = (px < 2) ? wlo : whi;
            const float soob =
                fabsf(pv[r][0][px]) + fabsf(pv[r][1][px]) + fabsf(pv[r][2][px]);
            best[r][px] = (hcand || wcand) ? soob : BIGF;
        }
    }

    // ---- 8 target rows, branch-free (clamped addresses) ----
#pragma unroll
    for (int j = 0; j < 8; ++j) {
        const int hh = h0 - 2 + j;                       // wave-uniform
        const bool rowok = (hh >= 0) && (hh < H_DIM);    // wave-uniform
        const int hc = (hh < 0) ? 0 : ((hh >= H_DIM) ? (H_DIM - 1) : hh);

        // 8-float window per channel: cols [w0-2, w0+6), unconditional loads
        float w[3][8];
#pragma unroll
        for (int c = 0; c < 3; ++c) {
            const float* rowp = trow + (size_t)c * HW + (size_t)hc * W_DIM;
            const f4 a = *(const f4*)(rowp + am);
            const f4 b = *(const f4*)(rowp + bp);
            w[c][0] = a[0];
            w[c][1] = a[1];
            w[c][2] = wlo ? a[0] : a[2];   // col 0 at left edge
            w[c][3] = wlo ? a[1] : a[3];   // col 1 at left edge
            w[c][4] = whi ? b[2] : b[0];   // col 510 at right edge
            w[c][5] = whi ? b[3] : b[1];   // col 511 at right edge
            w[c][6] = b[2];
            w[c][7] = b[3];
        }

#pragma unroll
        for (int r = 0; r < 4; ++r) {
            const int di = j - 2 - r;          // compile-time after unroll
            if (di >= -2 && di <= 2) {
#pragma unroll
                for (int px = 0; px < 4; ++px) {
                    float rm = BIGF;           // min over dj for this row
#pragma unroll
                    for (int dj = -2; dj <= 2; ++dj) {
                        const int ix = px + dj + 2;  // 0..7
                        float s = fabsf(pv[r][0][px] - w[0][ix])
                                + fabsf(pv[r][1][px] - w[1][ix])
                                + fabsf(pv[r][2][px] - w[2][ix]);
                        // out-of-image candidates invalid at w edges:
                        if (px + dj < 0)      s = wlo ? BIGF : s;
                        else if (px + dj > 3) s = whi ? BIGF : s;
                        rm = fminf(rm, s);
                    }
                    // suppress clamped (out-of-image) rows — wave-uniform:
                    best[r][px] = fminf(best[r][px], rowok ? rm : BIGF);
                }
            }
        }
    }

    // ---- block reduce: 16 px -> thread, wave shuffle, LDS, one atomic ----
    float v = 0.0f;
#pragma unroll
    for (int r = 0; r < 4; ++r)
#pragma unroll
        for (int px = 0; px < 4; ++px)
            v += best[r][px];

#pragma unroll
    for (int o = 32; o > 0; o >>= 1) v += __shfl_down(v, o, 64);

    __shared__ float ws[4];
    const int lane = tid & 63;
    const int wv   = tid >> 6;
    if (lane == 0) ws[wv] = v;
    __syncthreads();
    if (tid == 0) {
        const float bs = ws[0] + ws[1] + ws[2] + ws[3];
        atomicAdd(out, bs * (1.0f / (3.0f * (float)NPIX)));
    }
}

extern "C" void kernel_launch(void* const* d_in, const int* in_sizes, int n_in,
                              void* d_out, int out_size, void* d_ws, size_t ws_size,
                              hipStream_t stream) {
    const float* pred = (const float*)d_in[0];
    const float* targ = (const float*)d_in[1];
    float* out = (float*)d_out;

    hipMemsetAsync(out, 0, sizeof(float), stream);
    cvl_main<<<NBLOCKS, 256, 0, stream>>>(pred, targ, out);
}